// Round 6
// baseline (509.316 us; speedup 1.0000x reference)
//
#include <hip/hip_runtime.h>
#include <hip/hip_bf16.h>

#define VN 50000
#define EN 800000
#define BN 4
#define CINN 64
#define COUTN 128
#define KN 4
#define FN 256  // BN * CINN

typedef __attribute__((ext_vector_type(8))) short short8;
typedef __attribute__((ext_vector_type(8))) unsigned short ushort8;
typedef __attribute__((ext_vector_type(4))) float floatx4;

__device__ __forceinline__ float bf2f(unsigned short u) {
    union { unsigned int i; float f; } c;
    c.i = ((unsigned int)u) << 16;
    return c.f;
}
__device__ __forceinline__ unsigned short f2bf(float f) {
    __hip_bfloat16 h = __float2bfloat16(f);
    return *reinterpret_cast<unsigned short*>(&h);
}

#define RP_BLOCKS 196    // (VN+1+255)/256
#define WT_BLOCKS 128    // 128*256/256
#define EP_BLOCKS 3125   // EN/256
#define TP_BX 782        // (VN+63)/64
#define TP_BLOCKS (TP_BX * 4)
#define SPMM_BLOCKS (TP_BX * 8)  // 782 row-blocks (64 rows) x 8 feature slices

// ---------------------------------------------------------------------------
// Fused setup (round-1 version, verified): row_ptr lower_bound; wT
// transpose+bf16; packed (col,val) 8B edge records; 64x64 x-transpose
// fp32->bf16 into SLICED layout x0[plane][v][32], plane = f>>5.
// ---------------------------------------------------------------------------
__global__ __launch_bounds__(256) void setup_fused(const int* __restrict__ rows,
                                                   int* __restrict__ row_ptr,
                                                   const float* __restrict__ w,
                                                   ushort* __restrict__ wT,
                                                   const float* __restrict__ x,
                                                   ushort* __restrict__ x0,
                                                   const int* __restrict__ cols,
                                                   const float* __restrict__ vals,
                                                   unsigned long long* __restrict__ epack) {
    __shared__ float tile[64][65];
    int blk = blockIdx.x;
    int tid = threadIdx.x;
    if (blk < RP_BLOCKS) {
        int v = blk * 256 + tid;
        if (v > VN) return;
        int lo = 0, hi = EN;
        while (lo < hi) {
            int mid = (lo + hi) >> 1;
            if (rows[mid] < v) lo = mid + 1; else hi = mid;
        }
        row_ptr[v] = lo;
        return;
    }
    if (blk < RP_BLOCKS + WT_BLOCKS) {
        int idx = (blk - RP_BLOCKS) * 256 + tid;  // 32768 total
        int o = idx >> 8;
        int kk = idx & 255;
        wT[idx] = f2bf(w[(size_t)kk * COUTN + o]);
        return;
    }
    if (blk < RP_BLOCKS + WT_BLOCKS + EP_BLOCKS) {
        int idx = (blk - RP_BLOCKS - WT_BLOCKS) * 256 + tid;  // 800000 total
        unsigned int c = (unsigned int)cols[idx];
        unsigned int wv = __float_as_uint(vals[idx]);
        epack[idx] = ((unsigned long long)wv << 32) | (unsigned long long)c;
        return;
    }
    int t = blk - RP_BLOCKS - WT_BLOCKS - EP_BLOCKS;
    int v0 = (t % TP_BX) * 64;
    int f0 = (t / TP_BX) * 64;
    int tx = tid & 63;
    int ty = tid >> 6;
#pragma unroll
    for (int r = 0; r < 16; ++r) {
        int f = f0 + ty + r * 4;
        int v = v0 + tx;
        if (v < VN) tile[ty + r * 4][tx] = x[(size_t)f * VN + v];
    }
    __syncthreads();
#pragma unroll
    for (int r = 0; r < 16; ++r) {
        int v = v0 + ty + r * 4;
        int f = f0 + tx;
        if (v < VN)
            x0[((size_t)(f >> 5) * VN + v) * 32 + (f & 31)] = f2bf(tile[tx][ty + r * 4]);
    }
}

// ---------------------------------------------------------------------------
// Sliced SpMM, attempt 3. slice s = bid&7 -> pinned to one XCD by the
// round-robin workgroup dispatch (consecutive bids -> consecutive XCDs, the
// same mechanism HK's chiplet swizzle exploits). Each slice gathers only
// from its own 3.2MB plane (fits the XCD's 4MB L2; 16x reuse per line per
// pass). Diffs vs the round-1 version that regressed:
//   - z gathers, prev reads, out stores: ALL NORMAL cached (round-1's
//     nt-store of out pushed next pass's gather target to HBM = the
//     1.5TB/s latency disaster).
//   - nt retained ONLY on the epack stream (6.4MB/XCD/pass must not evict
//     the hot plane; its HBM cost ~8us/pass is priced in).
//   - no atomics / queues (round-2's cross-XCD qctr ping-pong serialized).
// Wave = 16 groups x 4 lanes; group owns a row; lane owns 8 features.
// 4-deep edge pipeline, two accumulators.
// ---------------------------------------------------------------------------
__global__ __launch_bounds__(256) void spmm_sliced(ushort* __restrict__ out,
                                                   const ushort* __restrict__ z,
                                                   const ushort* __restrict__ prev,
                                                   const int* __restrict__ row_ptr,
                                                   const unsigned long long* __restrict__ epack,
                                                   float alpha, float beta) {
    int bid = blockIdx.x;
    int s = bid & 7;            // feature slice -> XCD pin
    int rb = bid >> 3;          // row block (64 rows)
    int tid = threadIdx.x;
    int lane = tid & 63;
    int g = lane >> 2;          // group 0..15 within wave
    int l = lane & 3;           // lane in group: features l*8 .. l*8+7
    int r = rb * 64 + (tid >> 6) * 16 + g;
    if (r >= VN) return;

    const ushort* zs = z + (size_t)s * VN * 32 + l * 8;
    int e0 = row_ptr[r];
    int e1 = row_ptr[r + 1];

    float acc[8], acc2[8];
#pragma unroll
    for (int j = 0; j < 8; ++j) { acc[j] = 0.f; acc2[j] = 0.f; }

    int e = e0;
    for (; e + 3 < e1; e += 4) {
        unsigned long long d0 = __builtin_nontemporal_load(epack + e);
        unsigned long long d1 = __builtin_nontemporal_load(epack + e + 1);
        unsigned long long d2 = __builtin_nontemporal_load(epack + e + 2);
        unsigned long long d3 = __builtin_nontemporal_load(epack + e + 3);
        ushort8 z0 = *reinterpret_cast<const ushort8*>(zs + (size_t)(unsigned int)d0 * 32);
        ushort8 z1 = *reinterpret_cast<const ushort8*>(zs + (size_t)(unsigned int)d1 * 32);
        ushort8 z2 = *reinterpret_cast<const ushort8*>(zs + (size_t)(unsigned int)d2 * 32);
        ushort8 z3 = *reinterpret_cast<const ushort8*>(zs + (size_t)(unsigned int)d3 * 32);
        float w0 = __uint_as_float((unsigned int)(d0 >> 32));
        float w1 = __uint_as_float((unsigned int)(d1 >> 32));
        float w2 = __uint_as_float((unsigned int)(d2 >> 32));
        float w3 = __uint_as_float((unsigned int)(d3 >> 32));
#pragma unroll
        for (int j = 0; j < 8; ++j) acc[j] += w0 * bf2f(z0[j]);
#pragma unroll
        for (int j = 0; j < 8; ++j) acc2[j] += w1 * bf2f(z1[j]);
#pragma unroll
        for (int j = 0; j < 8; ++j) acc[j] += w2 * bf2f(z2[j]);
#pragma unroll
        for (int j = 0; j < 8; ++j) acc2[j] += w3 * bf2f(z3[j]);
    }
    for (; e < e1; ++e) {
        unsigned long long d = __builtin_nontemporal_load(epack + e);
        ushort8 zz = *reinterpret_cast<const ushort8*>(zs + (size_t)(unsigned int)d * 32);
        float w = __uint_as_float((unsigned int)(d >> 32));
#pragma unroll
        for (int j = 0; j < 8; ++j) acc[j] += w * bf2f(zz[j]);
    }
#pragma unroll
    for (int j = 0; j < 8; ++j) acc[j] += acc2[j];

    size_t off = ((size_t)s * VN + r) * 32 + l * 8;
    ushort8 res;
    if (beta != 0.f) {
        ushort8 pv = *reinterpret_cast<const ushort8*>(prev + off);
#pragma unroll
        for (int j = 0; j < 8; ++j) res[j] = f2bf(alpha * acc[j] + beta * bf2f(pv[j]));
    } else {
#pragma unroll
        for (int j = 0; j < 8; ++j) res[j] = f2bf(alpha * acc[j]);
    }
    *reinterpret_cast<ushort8*>(out + off) = res;
}

// ---------------------------------------------------------------------------
// MFMA GEMM (round-1 version, verified; = v1 structure reading sliced x):
// out[b,o,v] = sum_k wT[o][k] * xk(v,b-slice)[k] + bias[o]
// A = wT (M=o=128), B = x rows (N=v, 128/block). LDS XOR swizzle. Delta this
// round: nt final stores (out never re-read; avoid L2 write-allocate
// evicting x0 lines mid-kernel).
// ---------------------------------------------------------------------------
__global__ __launch_bounds__(256) void cheb_gemm_mfma(float* __restrict__ out,
                                                      const ushort* __restrict__ xbase,
                                                      const ushort* __restrict__ wT,
                                                      const float* __restrict__ bias) {
    __shared__ __align__(16) short lsA[128 * 64];
    __shared__ __align__(16) short lsB[128 * 64];

    int b = blockIdx.y;
    int v0 = blockIdx.x * 128;
    int tid = threadIdx.x;
    int lane = tid & 63;
    int w = tid >> 6;
    int mw = w & 1;
    int nw = w >> 1;
    int ln = lane & 15;
    int quad = lane >> 4;

    int srow = tid >> 1;
    int posBase = (tid & 1) * 4;

    floatx4 acc[4][4];
#pragma unroll
    for (int mi = 0; mi < 4; ++mi)
#pragma unroll
        for (int ni = 0; ni < 4; ++ni) acc[mi][ni] = (floatx4){0.f, 0.f, 0.f, 0.f};

    for (int kc = 0; kc < 4; ++kc) {
        __syncthreads();
        // stage A: wT rows (o)
#pragma unroll
        for (int j = 0; j < 4; ++j) {
            int pos = posBase + j;
            int g = pos ^ (srow & 7);
            uint4 val = *reinterpret_cast<const uint4*>(wT + (size_t)srow * 256 + kc * 64 + g * 8);
            *reinterpret_cast<uint4*>(&lsA[(srow * 8 + pos) * 8]) = val;
        }
        // stage B: xk bf16, sliced layout [plane][VN][32]
        {
            const ushort* xk = xbase + (size_t)kc * VN * FN;
            int v = v0 + srow;
            bool ok = (v < VN);
#pragma unroll
            for (int j = 0; j < 4; ++j) {
                int pos = posBase + j;
                int g = pos ^ (srow & 7);
                int p = b * 2 + (g >> 2);          // global feature plane
                const ushort* src = xk + ((size_t)p * VN + v) * 32 + (g & 3) * 8;
                uint4 val;
                if (ok) val = *reinterpret_cast<const uint4*>(src);
                else    val = make_uint4(0u, 0u, 0u, 0u);
                *reinterpret_cast<uint4*>(&lsB[(srow * 8 + pos) * 8]) = val;
            }
        }
        __syncthreads();

#pragma unroll
        for (int s = 0; s < 2; ++s) {
            short8 afr[4], bfr[4];
#pragma unroll
            for (int mi = 0; mi < 4; ++mi) {
                int r = mw * 64 + mi * 16 + ln;
                int pos = (s * 4 + quad) ^ (r & 7);
                afr[mi] = *reinterpret_cast<const short8*>(&lsA[(r * 8 + pos) * 8]);
            }
#pragma unroll
            for (int ni = 0; ni < 4; ++ni) {
                int r = nw * 64 + ni * 16 + ln;
                int pos = (s * 4 + quad) ^ (r & 7);
                bfr[ni] = *reinterpret_cast<const short8*>(&lsB[(r * 8 + pos) * 8]);
            }
#pragma unroll
            for (int mi = 0; mi < 4; ++mi)
#pragma unroll
                for (int ni = 0; ni < 4; ++ni)
                    acc[mi][ni] = __builtin_amdgcn_mfma_f32_16x16x32_bf16(
                        afr[mi], bfr[ni], acc[mi][ni], 0, 0, 0);
        }
    }

#pragma unroll
    for (int mi = 0; mi < 4; ++mi) {
#pragma unroll
        for (int r = 0; r < 4; ++r) {
            int o = mw * 64 + mi * 16 + quad * 4 + r;
            float bv = bias[o];
            size_t obase = (size_t)(b * COUTN + o) * VN;
#pragma unroll
            for (int ni = 0; ni < 4; ++ni) {
                int v = v0 + nw * 64 + ni * 16 + ln;
                if (v < VN) __builtin_nontemporal_store(acc[mi][ni][r] + bv, &out[obase + v]);
            }
        }
    }
}

// ---------------------------------------------------------------------------
extern "C" void kernel_launch(void* const* d_in, const int* in_sizes, int n_in,
                              void* d_out, int out_size, void* d_ws, size_t ws_size,
                              hipStream_t stream) {
    const float* x        = (const float*)d_in[0];
    const int*   lap_rows = (const int*)d_in[1];
    const int*   lap_cols = (const int*)d_in[2];
    const float* lap_vals = (const float*)d_in[3];
    const float* weight   = (const float*)d_in[4];
    const float* bias     = (const float*)d_in[5];
    float* out = (float*)d_out;

    char* ws = (char*)d_ws;
    ushort* x0 = (ushort*)ws;                        // 4 x [8][V][32] bf16, contiguous
    ushort* x1 = x0 + (size_t)VN * FN;
    ushort* x2 = x1 + (size_t)VN * FN;
    ushort* x3 = x2 + (size_t)VN * FN;
    size_t xbytes = (size_t)4 * VN * FN * sizeof(ushort);
    int* row_ptr = (int*)(ws + xbytes);              // V+1 ints
    size_t rp_end = xbytes + (size_t)(VN + 1) * sizeof(int);
    rp_end = (rp_end + 15) & ~(size_t)15;            // 16B align
    ushort* wT = (ushort*)(ws + rp_end);             // (128,256) bf16 = 64KB
    size_t wt_end = rp_end + (size_t)COUTN * FN * sizeof(ushort);
    unsigned long long* epack = (unsigned long long*)(ws + wt_end);  // 6.4MB

    setup_fused<<<RP_BLOCKS + WT_BLOCKS + EP_BLOCKS + TP_BLOCKS, 256, 0, stream>>>(
        lap_rows, row_ptr, weight, wT, x, x0, lap_cols, lap_vals, epack);
    // x1 = L x0
    spmm_sliced<<<SPMM_BLOCKS, 256, 0, stream>>>(x1, x0, x0, row_ptr, epack, 1.f, 0.f);
    // x2 = 2 L x1 - x0
    spmm_sliced<<<SPMM_BLOCKS, 256, 0, stream>>>(x2, x1, x0, row_ptr, epack, 2.f, -1.f);
    // x3 = 2 L x2 - x1
    spmm_sliced<<<SPMM_BLOCKS, 256, 0, stream>>>(x3, x2, x1, row_ptr, epack, 2.f, -1.f);
    // out = sum_k xk @ Wk + bias  (MFMA)
    cheb_gemm_mfma<<<dim3((VN + 127) / 128, BN), 256, 0, stream>>>(out, x0, wT, bias);
}

// Round 7
// 401.463 us; speedup vs baseline: 1.2687x; 1.2687x over previous
//
#include <hip/hip_runtime.h>
#include <hip/hip_bf16.h>

#define VN 50000
#define EN 800000
#define BN 4
#define CINN 64
#define COUTN 128
#define KN 4
#define FN 256  // BN * CINN

typedef __attribute__((ext_vector_type(8))) short short8;
typedef __attribute__((ext_vector_type(8))) unsigned short ushort8;
typedef __attribute__((ext_vector_type(4))) float floatx4;

__device__ __forceinline__ float bf2f(unsigned short u) {
    union { unsigned int i; float f; } c;
    c.i = ((unsigned int)u) << 16;
    return c.f;
}
__device__ __forceinline__ unsigned short f2bf(float f) {
    __hip_bfloat16 h = __float2bfloat16(f);
    return *reinterpret_cast<unsigned short*>(&h);
}

#define RP_BLOCKS 196    // (VN+1+255)/256
#define WT_BLOCKS 128    // 128*256/256
#define EP_BLOCKS 3125   // EN/256
#define TP_BX 782        // (VN+63)/64
#define TP_BLOCKS (TP_BX * 4)

// ---------------------------------------------------------------------------
// Fused setup (round-4, known-good): row_ptr lower_bound; wT transpose+bf16;
// packed (col,val) 8B edge records; 64x64 x-transpose fp32->bf16 into
// interleaved layout x0[v][256].
// ---------------------------------------------------------------------------
__global__ __launch_bounds__(256) void setup_fused(const int* __restrict__ rows,
                                                   int* __restrict__ row_ptr,
                                                   const float* __restrict__ w,
                                                   ushort* __restrict__ wT,
                                                   const float* __restrict__ x,
                                                   ushort* __restrict__ x0,
                                                   const int* __restrict__ cols,
                                                   const float* __restrict__ vals,
                                                   unsigned long long* __restrict__ epack) {
    __shared__ float tile[64][65];
    int blk = blockIdx.x;
    int tid = threadIdx.x;
    if (blk < RP_BLOCKS) {
        int v = blk * 256 + tid;
        if (v > VN) return;
        int lo = 0, hi = EN;
        while (lo < hi) {
            int mid = (lo + hi) >> 1;
            if (rows[mid] < v) lo = mid + 1; else hi = mid;
        }
        row_ptr[v] = lo;
        return;
    }
    if (blk < RP_BLOCKS + WT_BLOCKS) {
        int idx = (blk - RP_BLOCKS) * 256 + tid;  // 32768 total
        int o = idx >> 8;
        int kk = idx & 255;
        wT[idx] = f2bf(w[(size_t)kk * COUTN + o]);
        return;
    }
    if (blk < RP_BLOCKS + WT_BLOCKS + EP_BLOCKS) {
        int idx = (blk - RP_BLOCKS - WT_BLOCKS) * 256 + tid;  // 800000 total
        unsigned int c = (unsigned int)cols[idx];
        unsigned int wv = __float_as_uint(vals[idx]);
        epack[idx] = ((unsigned long long)wv << 32) | (unsigned long long)c;
        return;
    }
    int t = blk - RP_BLOCKS - WT_BLOCKS - EP_BLOCKS;
    int v0 = (t % TP_BX) * 64;
    int f0 = (t / TP_BX) * 64;
    int tx = tid & 63;
    int ty = tid >> 6;
#pragma unroll
    for (int r = 0; r < 16; ++r) {
        int f = f0 + ty + r * 4;
        int v = v0 + tx;
        if (v < VN) tile[ty + r * 4][tx] = x[(size_t)f * VN + v];
    }
    __syncthreads();
#pragma unroll
    for (int r = 0; r < 16; ++r) {
        int v = v0 + ty + r * 4;
        int f = f0 + tx;
        if (v < VN) x0[(size_t)v * FN + f] = f2bf(tile[tx][ty + r * 4]);
    }
}

// ---------------------------------------------------------------------------
// bf16 SpMM (round-4, known-good, UNCHANGED — pinned at ~61us by the
// gather L2-miss path; metadata changes moved nothing): out[v,:] =
// alpha*sum_e w_e*z[c_e,:] + beta*prev[v,:]. One wave per vertex; halves on
// even/odd edges; lane owns 8 features; 4-deep gather pipeline per half.
// ---------------------------------------------------------------------------
__global__ __launch_bounds__(256) void spmm_cheb_bf16(ushort* __restrict__ out,
                                                      const ushort* __restrict__ z,
                                                      const ushort* __restrict__ prev,
                                                      const int* __restrict__ row_ptr,
                                                      const unsigned long long* __restrict__ epack,
                                                      float alpha, float beta) {
    int row = (int)((blockIdx.x * blockDim.x + threadIdx.x) >> 6);
    int lane = threadIdx.x & 63;
    if (row >= VN) return;
    int e0 = row_ptr[row];
    int e1 = row_ptr[row + 1];
    int half = lane >> 5;        // 0: even edges, 1: odd edges
    int fl = (lane & 31) * 8;    // 8 features per lane

    float acc0[8], acc1[8];
#pragma unroll
    for (int j = 0; j < 8; ++j) { acc0[j] = 0.f; acc1[j] = 0.f; }

    int e = e0 + half;
    // 4-deep main loop: 4 gathers in flight per half
    for (; e + 6 < e1; e += 8) {
        unsigned long long d0 = epack[e];
        unsigned long long d1 = epack[e + 2];
        unsigned long long d2 = epack[e + 4];
        unsigned long long d3 = epack[e + 6];
        ushort8 z0 = *reinterpret_cast<const ushort8*>(z + (size_t)(unsigned int)d0 * FN + fl);
        ushort8 z1 = *reinterpret_cast<const ushort8*>(z + (size_t)(unsigned int)d1 * FN + fl);
        ushort8 z2 = *reinterpret_cast<const ushort8*>(z + (size_t)(unsigned int)d2 * FN + fl);
        ushort8 z3 = *reinterpret_cast<const ushort8*>(z + (size_t)(unsigned int)d3 * FN + fl);
        float w0 = __uint_as_float((unsigned int)(d0 >> 32));
        float w1 = __uint_as_float((unsigned int)(d1 >> 32));
        float w2 = __uint_as_float((unsigned int)(d2 >> 32));
        float w3 = __uint_as_float((unsigned int)(d3 >> 32));
#pragma unroll
        for (int j = 0; j < 8; ++j) acc0[j] += w0 * bf2f(z0[j]);
#pragma unroll
        for (int j = 0; j < 8; ++j) acc1[j] += w1 * bf2f(z1[j]);
#pragma unroll
        for (int j = 0; j < 8; ++j) acc0[j] += w2 * bf2f(z2[j]);
#pragma unroll
        for (int j = 0; j < 8; ++j) acc1[j] += w3 * bf2f(z3[j]);
    }
    // 2-deep remainder
    for (; e + 2 < e1; e += 4) {
        unsigned long long d0 = epack[e];
        unsigned long long d1 = epack[e + 2];
        ushort8 z0 = *reinterpret_cast<const ushort8*>(z + (size_t)(unsigned int)d0 * FN + fl);
        ushort8 z1 = *reinterpret_cast<const ushort8*>(z + (size_t)(unsigned int)d1 * FN + fl);
        float w0 = __uint_as_float((unsigned int)(d0 >> 32));
        float w1 = __uint_as_float((unsigned int)(d1 >> 32));
#pragma unroll
        for (int j = 0; j < 8; ++j) acc0[j] += w0 * bf2f(z0[j]);
#pragma unroll
        for (int j = 0; j < 8; ++j) acc1[j] += w1 * bf2f(z1[j]);
    }
    for (; e < e1; e += 2) {
        unsigned long long d0 = epack[e];
        ushort8 z0 = *reinterpret_cast<const ushort8*>(z + (size_t)(unsigned int)d0 * FN + fl);
        float w0 = __uint_as_float((unsigned int)(d0 >> 32));
#pragma unroll
        for (int j = 0; j < 8; ++j) acc0[j] += w0 * bf2f(z0[j]);
    }
#pragma unroll
    for (int j = 0; j < 8; ++j) acc0[j] += acc1[j];
    // butterfly: merge even/odd halves
#pragma unroll
    for (int j = 0; j < 8; ++j) acc0[j] += __shfl(acc0[j], lane ^ 32);

    if (half == 0) {
        ushort8 res;
        if (beta != 0.f) {
            ushort8 pv = *reinterpret_cast<const ushort8*>(prev + (size_t)row * FN + fl);
#pragma unroll
            for (int j = 0; j < 8; ++j)
                res[j] = f2bf(alpha * acc0[j] + beta * bf2f(pv[j]));
        } else {
#pragma unroll
            for (int j = 0; j < 8; ++j)
                res[j] = f2bf(alpha * acc0[j]);
        }
        *reinterpret_cast<ushort8*>(out + (size_t)row * FN + fl) = res;
    }
}

// ---------------------------------------------------------------------------
// MFMA GEMM v1 + T14 register prefetch (the ONLY change vs round 4):
// out[b,o,v] = sum_k wT[o][k] * x(v)[k] + bias[o]. A = wT (M=o=128),
// B = x rows (N=v, 128/block). LDS XOR swizzle and v1's fully-coalesced
// scalar epilogue (16 consecutive-v lanes x 4B = full 64B lines — r5's swap
// broke this and caused 280MB write amplification) are UNCHANGED.
// Prefetch: kc+1's A/B tiles loaded into registers right after the second
// barrier so global latency hides under the MFMA phase (was fully exposed
// 4x per block: MfmaUtil 8%, VALUBusy 9%, Occ 23% at 60.6us vs 32.5 floor).
// ---------------------------------------------------------------------------
__global__ __launch_bounds__(256) void cheb_gemm_mfma(float* __restrict__ out,
                                                      const ushort* __restrict__ xbase,
                                                      const ushort* __restrict__ wT,
                                                      const float* __restrict__ bias) {
    __shared__ __align__(16) short lsA[128 * 64];
    __shared__ __align__(16) short lsB[128 * 64];

    int b = blockIdx.y;
    int v0 = blockIdx.x * 128;
    int tid = threadIdx.x;
    int lane = tid & 63;
    int w = tid >> 6;
    int mw = w & 1;
    int nw = w >> 1;
    int ln = lane & 15;
    int quad = lane >> 4;

    int srow = tid >> 1;
    int posBase = (tid & 1) * 4;
    int v = v0 + srow;
    bool ok = (v < VN);

    floatx4 acc[4][4];
#pragma unroll
    for (int mi = 0; mi < 4; ++mi)
#pragma unroll
        for (int ni = 0; ni < 4; ++ni) acc[mi][ni] = (floatx4){0.f, 0.f, 0.f, 0.f};

    uint4 pA[4], pB[4];

#define LOADA(KC)                                                                        \
    {                                                                                    \
        _Pragma("unroll")                                                                \
        for (int j = 0; j < 4; ++j) {                                                    \
            int g = (posBase + j) ^ (srow & 7);                                          \
            pA[j] = *reinterpret_cast<const uint4*>(wT + (size_t)srow * 256 + (KC) * 64 + g * 8); \
        }                                                                                \
    }
#define LOADB(KC)                                                                        \
    {                                                                                    \
        const ushort* src = xbase + (size_t)(KC) * VN * FN + (size_t)v * FN + b * CINN;  \
        _Pragma("unroll")                                                                \
        for (int j = 0; j < 4; ++j) {                                                    \
            int g = (posBase + j) ^ (srow & 7);                                          \
            if (ok) pB[j] = *reinterpret_cast<const uint4*>(src + g * 8);                \
            else    pB[j] = make_uint4(0u, 0u, 0u, 0u);                                  \
        }                                                                                \
    }

    LOADA(0);
    LOADB(0);

    for (int kc = 0; kc < 4; ++kc) {
        __syncthreads();   // previous phase's LDS reads complete
#pragma unroll
        for (int j = 0; j < 4; ++j) {
            int pos = posBase + j;
            *reinterpret_cast<uint4*>(&lsA[(srow * 8 + pos) * 8]) = pA[j];
            *reinterpret_cast<uint4*>(&lsB[(srow * 8 + pos) * 8]) = pB[j];
        }
        __syncthreads();

        if (kc < 3) {      // prefetch next kc while this kc's MFMAs run
            LOADA(kc + 1);
            LOADB(kc + 1);
        }

#pragma unroll
        for (int s = 0; s < 2; ++s) {
            short8 afr[4], bfr[4];
#pragma unroll
            for (int mi = 0; mi < 4; ++mi) {
                int r = mw * 64 + mi * 16 + ln;
                int pos = (s * 4 + quad) ^ (r & 7);
                afr[mi] = *reinterpret_cast<const short8*>(&lsA[(r * 8 + pos) * 8]);
            }
#pragma unroll
            for (int ni = 0; ni < 4; ++ni) {
                int r = nw * 64 + ni * 16 + ln;
                int pos = (s * 4 + quad) ^ (r & 7);
                bfr[ni] = *reinterpret_cast<const short8*>(&lsB[(r * 8 + pos) * 8]);
            }
#pragma unroll
            for (int mi = 0; mi < 4; ++mi)
#pragma unroll
                for (int ni = 0; ni < 4; ++ni)
                    acc[mi][ni] = __builtin_amdgcn_mfma_f32_16x16x32_bf16(
                        afr[mi], bfr[ni], acc[mi][ni], 0, 0, 0);
        }
    }
#undef LOADA
#undef LOADB

    // epilogue (v1, unchanged): 16 consecutive-v lanes x 4B = full 64B lines
#pragma unroll
    for (int mi = 0; mi < 4; ++mi) {
#pragma unroll
        for (int r = 0; r < 4; ++r) {
            int o = mw * 64 + mi * 16 + quad * 4 + r;
            float bv = bias[o];
            size_t obase = (size_t)(b * COUTN + o) * VN;
#pragma unroll
            for (int ni = 0; ni < 4; ++ni) {
                int vv = v0 + nw * 64 + ni * 16 + ln;
                if (vv < VN) out[obase + vv] = acc[mi][ni][r] + bv;
            }
        }
    }
}

// ---------------------------------------------------------------------------
extern "C" void kernel_launch(void* const* d_in, const int* in_sizes, int n_in,
                              void* d_out, int out_size, void* d_ws, size_t ws_size,
                              hipStream_t stream) {
    const float* x        = (const float*)d_in[0];
    const int*   lap_rows = (const int*)d_in[1];
    const int*   lap_cols = (const int*)d_in[2];
    const float* lap_vals = (const float*)d_in[3];
    const float* weight   = (const float*)d_in[4];
    const float* bias     = (const float*)d_in[5];
    float* out = (float*)d_out;

    char* ws = (char*)d_ws;
    ushort* x0 = (ushort*)ws;                        // 4 x (V,256) bf16, contiguous
    ushort* x1 = x0 + (size_t)VN * FN;
    ushort* x2 = x1 + (size_t)VN * FN;
    ushort* x3 = x2 + (size_t)VN * FN;
    size_t xbytes = (size_t)4 * VN * FN * sizeof(ushort);
    int* row_ptr = (int*)(ws + xbytes);              // V+1 ints
    size_t rp_end = xbytes + (size_t)(VN + 1) * sizeof(int);
    rp_end = (rp_end + 15) & ~(size_t)15;            // 16B align
    ushort* wT = (ushort*)(ws + rp_end);             // (128,256) bf16 = 64KB
    size_t wt_end = rp_end + (size_t)COUTN * FN * sizeof(ushort);
    unsigned long long* epack = (unsigned long long*)(ws + wt_end);  // 6.4MB

    setup_fused<<<RP_BLOCKS + WT_BLOCKS + EP_BLOCKS + TP_BLOCKS, 256, 0, stream>>>(
        lap_rows, row_ptr, weight, wT, x, x0, lap_cols, lap_vals, epack);
    // x1 = L x0
    spmm_cheb_bf16<<<(VN + 3) / 4, 256, 0, stream>>>(x1, x0, x0, row_ptr, epack, 1.f, 0.f);
    // x2 = 2 L x1 - x0
    spmm_cheb_bf16<<<(VN + 3) / 4, 256, 0, stream>>>(x2, x1, x0, row_ptr, epack, 2.f, -1.f);
    // x3 = 2 L x2 - x1
    spmm_cheb_bf16<<<(VN + 3) / 4, 256, 0, stream>>>(x3, x2, x1, row_ptr, epack, 2.f, -1.f);
    // out = sum_k xk @ Wk + bias  (MFMA)
    cheb_gemm_mfma<<<dim3((VN + 127) / 128, BN), 256, 0, stream>>>(out, x0, wT, bias);
}

// Round 8
// 384.633 us; speedup vs baseline: 1.3242x; 1.0438x over previous
//
#include <hip/hip_runtime.h>
#include <hip/hip_bf16.h>

#define VN 50000
#define EN 800000
#define BN 4
#define CINN 64
#define COUTN 128
#define KN 4
#define FN 256  // BN * CINN

typedef __attribute__((ext_vector_type(8))) short short8;
typedef __attribute__((ext_vector_type(8))) unsigned short ushort8;
typedef __attribute__((ext_vector_type(4))) float floatx4;

__device__ __forceinline__ float bf2f(unsigned short u) {
    union { unsigned int i; float f; } c;
    c.i = ((unsigned int)u) << 16;
    return c.f;
}
__device__ __forceinline__ unsigned short f2bf(float f) {
    __hip_bfloat16 h = __float2bfloat16(f);
    return *reinterpret_cast<unsigned short*>(&h);
}

#define RP_BLOCKS 196    // (VN+1+255)/256
#define WT_BLOCKS 128    // 128*256/256
#define EP_BLOCKS 3125   // EN/256
#define TP_BX 782        // (VN+63)/64
#define TP_BLOCKS (TP_BX * 4)

// ---------------------------------------------------------------------------
// Fused setup (round-4, known-good): row_ptr lower_bound; wT transpose+bf16;
// packed (col,val) 8B edge records; 64x64 x-transpose fp32->bf16 into
// interleaved layout x0[v][256].
// ---------------------------------------------------------------------------
__global__ __launch_bounds__(256) void setup_fused(const int* __restrict__ rows,
                                                   int* __restrict__ row_ptr,
                                                   const float* __restrict__ w,
                                                   ushort* __restrict__ wT,
                                                   const float* __restrict__ x,
                                                   ushort* __restrict__ x0,
                                                   const int* __restrict__ cols,
                                                   const float* __restrict__ vals,
                                                   unsigned long long* __restrict__ epack) {
    __shared__ float tile[64][65];
    int blk = blockIdx.x;
    int tid = threadIdx.x;
    if (blk < RP_BLOCKS) {
        int v = blk * 256 + tid;
        if (v > VN) return;
        int lo = 0, hi = EN;
        while (lo < hi) {
            int mid = (lo + hi) >> 1;
            if (rows[mid] < v) lo = mid + 1; else hi = mid;
        }
        row_ptr[v] = lo;
        return;
    }
    if (blk < RP_BLOCKS + WT_BLOCKS) {
        int idx = (blk - RP_BLOCKS) * 256 + tid;  // 32768 total
        int o = idx >> 8;
        int kk = idx & 255;
        wT[idx] = f2bf(w[(size_t)kk * COUTN + o]);
        return;
    }
    if (blk < RP_BLOCKS + WT_BLOCKS + EP_BLOCKS) {
        int idx = (blk - RP_BLOCKS - WT_BLOCKS) * 256 + tid;  // 800000 total
        unsigned int c = (unsigned int)cols[idx];
        unsigned int wv = __float_as_uint(vals[idx]);
        epack[idx] = ((unsigned long long)wv << 32) | (unsigned long long)c;
        return;
    }
    int t = blk - RP_BLOCKS - WT_BLOCKS - EP_BLOCKS;
    int v0 = (t % TP_BX) * 64;
    int f0 = (t / TP_BX) * 64;
    int tx = tid & 63;
    int ty = tid >> 6;
#pragma unroll
    for (int r = 0; r < 16; ++r) {
        int f = f0 + ty + r * 4;
        int v = v0 + tx;
        if (v < VN) tile[ty + r * 4][tx] = x[(size_t)f * VN + v];
    }
    __syncthreads();
#pragma unroll
    for (int r = 0; r < 16; ++r) {
        int v = v0 + ty + r * 4;
        int f = f0 + tx;
        if (v < VN) x0[(size_t)v * FN + f] = f2bf(tile[tx][ty + r * 4]);
    }
}

// ---------------------------------------------------------------------------
// bf16 SpMM. Round-4 structure; single change this round: gather pipeline
// deepened 4 -> 8 per half (16 in flight per wave). Diagnosis: r4 counters
// show VALUBusy 39%, HBM 45%, Occ 68% -> gather-LATENCY-bound; ~48 extra
// VGPRs (32 -> ~80) buys 2x outstanding gathers, no occupancy cost.
// ---------------------------------------------------------------------------
__global__ __launch_bounds__(256) void spmm_cheb_bf16(ushort* __restrict__ out,
                                                      const ushort* __restrict__ z,
                                                      const ushort* __restrict__ prev,
                                                      const int* __restrict__ row_ptr,
                                                      const unsigned long long* __restrict__ epack,
                                                      float alpha, float beta) {
    int row = (int)((blockIdx.x * blockDim.x + threadIdx.x) >> 6);
    int lane = threadIdx.x & 63;
    if (row >= VN) return;
    int e0 = row_ptr[row];
    int e1 = row_ptr[row + 1];
    int half = lane >> 5;        // 0: even edges, 1: odd edges
    int fl = (lane & 31) * 8;    // 8 features per lane

    float acc0[8], acc1[8];
#pragma unroll
    for (int j = 0; j < 8; ++j) { acc0[j] = 0.f; acc1[j] = 0.f; }

    int e = e0 + half;
    // 8-deep main loop: 8 gathers in flight per half (16 per wave)
    for (; e + 14 < e1; e += 16) {
        unsigned long long d0 = epack[e];
        unsigned long long d1 = epack[e + 2];
        unsigned long long d2 = epack[e + 4];
        unsigned long long d3 = epack[e + 6];
        unsigned long long d4 = epack[e + 8];
        unsigned long long d5 = epack[e + 10];
        unsigned long long d6 = epack[e + 12];
        unsigned long long d7 = epack[e + 14];
        ushort8 z0 = *reinterpret_cast<const ushort8*>(z + (size_t)(unsigned int)d0 * FN + fl);
        ushort8 z1 = *reinterpret_cast<const ushort8*>(z + (size_t)(unsigned int)d1 * FN + fl);
        ushort8 z2 = *reinterpret_cast<const ushort8*>(z + (size_t)(unsigned int)d2 * FN + fl);
        ushort8 z3 = *reinterpret_cast<const ushort8*>(z + (size_t)(unsigned int)d3 * FN + fl);
        ushort8 z4 = *reinterpret_cast<const ushort8*>(z + (size_t)(unsigned int)d4 * FN + fl);
        ushort8 z5 = *reinterpret_cast<const ushort8*>(z + (size_t)(unsigned int)d5 * FN + fl);
        ushort8 z6 = *reinterpret_cast<const ushort8*>(z + (size_t)(unsigned int)d6 * FN + fl);
        ushort8 z7 = *reinterpret_cast<const ushort8*>(z + (size_t)(unsigned int)d7 * FN + fl);
        float w0 = __uint_as_float((unsigned int)(d0 >> 32));
        float w1 = __uint_as_float((unsigned int)(d1 >> 32));
        float w2 = __uint_as_float((unsigned int)(d2 >> 32));
        float w3 = __uint_as_float((unsigned int)(d3 >> 32));
        float w4 = __uint_as_float((unsigned int)(d4 >> 32));
        float w5 = __uint_as_float((unsigned int)(d5 >> 32));
        float w6 = __uint_as_float((unsigned int)(d6 >> 32));
        float w7 = __uint_as_float((unsigned int)(d7 >> 32));
#pragma unroll
        for (int j = 0; j < 8; ++j) acc0[j] += w0 * bf2f(z0[j]);
#pragma unroll
        for (int j = 0; j < 8; ++j) acc1[j] += w1 * bf2f(z1[j]);
#pragma unroll
        for (int j = 0; j < 8; ++j) acc0[j] += w2 * bf2f(z2[j]);
#pragma unroll
        for (int j = 0; j < 8; ++j) acc1[j] += w3 * bf2f(z3[j]);
#pragma unroll
        for (int j = 0; j < 8; ++j) acc0[j] += w4 * bf2f(z4[j]);
#pragma unroll
        for (int j = 0; j < 8; ++j) acc1[j] += w5 * bf2f(z5[j]);
#pragma unroll
        for (int j = 0; j < 8; ++j) acc0[j] += w6 * bf2f(z6[j]);
#pragma unroll
        for (int j = 0; j < 8; ++j) acc1[j] += w7 * bf2f(z7[j]);
    }
    // 4-deep remainder
    for (; e + 6 < e1; e += 8) {
        unsigned long long d0 = epack[e];
        unsigned long long d1 = epack[e + 2];
        unsigned long long d2 = epack[e + 4];
        unsigned long long d3 = epack[e + 6];
        ushort8 z0 = *reinterpret_cast<const ushort8*>(z + (size_t)(unsigned int)d0 * FN + fl);
        ushort8 z1 = *reinterpret_cast<const ushort8*>(z + (size_t)(unsigned int)d1 * FN + fl);
        ushort8 z2 = *reinterpret_cast<const ushort8*>(z + (size_t)(unsigned int)d2 * FN + fl);
        ushort8 z3 = *reinterpret_cast<const ushort8*>(z + (size_t)(unsigned int)d3 * FN + fl);
        float w0 = __uint_as_float((unsigned int)(d0 >> 32));
        float w1 = __uint_as_float((unsigned int)(d1 >> 32));
        float w2 = __uint_as_float((unsigned int)(d2 >> 32));
        float w3 = __uint_as_float((unsigned int)(d3 >> 32));
#pragma unroll
        for (int j = 0; j < 8; ++j) acc0[j] += w0 * bf2f(z0[j]);
#pragma unroll
        for (int j = 0; j < 8; ++j) acc1[j] += w1 * bf2f(z1[j]);
#pragma unroll
        for (int j = 0; j < 8; ++j) acc0[j] += w2 * bf2f(z2[j]);
#pragma unroll
        for (int j = 0; j < 8; ++j) acc1[j] += w3 * bf2f(z3[j]);
    }
    // 2-deep remainder
    for (; e + 2 < e1; e += 4) {
        unsigned long long d0 = epack[e];
        unsigned long long d1 = epack[e + 2];
        ushort8 z0 = *reinterpret_cast<const ushort8*>(z + (size_t)(unsigned int)d0 * FN + fl);
        ushort8 z1 = *reinterpret_cast<const ushort8*>(z + (size_t)(unsigned int)d1 * FN + fl);
        float w0 = __uint_as_float((unsigned int)(d0 >> 32));
        float w1 = __uint_as_float((unsigned int)(d1 >> 32));
#pragma unroll
        for (int j = 0; j < 8; ++j) acc0[j] += w0 * bf2f(z0[j]);
#pragma unroll
        for (int j = 0; j < 8; ++j) acc1[j] += w1 * bf2f(z1[j]);
    }
    for (; e < e1; e += 2) {
        unsigned long long d0 = epack[e];
        ushort8 z0 = *reinterpret_cast<const ushort8*>(z + (size_t)(unsigned int)d0 * FN + fl);
        float w0 = __uint_as_float((unsigned int)(d0 >> 32));
#pragma unroll
        for (int j = 0; j < 8; ++j) acc0[j] += w0 * bf2f(z0[j]);
    }
#pragma unroll
    for (int j = 0; j < 8; ++j) acc0[j] += acc1[j];
    // butterfly: merge even/odd halves
#pragma unroll
    for (int j = 0; j < 8; ++j) acc0[j] += __shfl(acc0[j], lane ^ 32);

    if (half == 0) {
        ushort8 res;
        if (beta != 0.f) {
            ushort8 pv = *reinterpret_cast<const ushort8*>(prev + (size_t)row * FN + fl);
#pragma unroll
            for (int j = 0; j < 8; ++j)
                res[j] = f2bf(alpha * acc0[j] + beta * bf2f(pv[j]));
        } else {
#pragma unroll
            for (int j = 0; j < 8; ++j)
                res[j] = f2bf(alpha * acc0[j]);
        }
        *reinterpret_cast<ushort8*>(out + (size_t)row * FN + fl) = res;
    }
}

// ---------------------------------------------------------------------------
// MFMA GEMM (EXACT round-4 v1, known-good 60.6us — rounds 5/7 proved
// register-carried prefetch across barriers spills to scratch here and
// regresses; do not re-add without a global_load_lds-based staging rewrite):
// out[b,o,v] = sum_k wT[o][k] * x(v)[k] + bias[o]. A = wT (M=o=128),
// B = x rows (N=v, 128/block). LDS XOR swizzle; coalesced scalar epilogue.
// ---------------------------------------------------------------------------
__global__ __launch_bounds__(256) void cheb_gemm_mfma(float* __restrict__ out,
                                                      const ushort* __restrict__ xbase,
                                                      const ushort* __restrict__ wT,
                                                      const float* __restrict__ bias) {
    __shared__ __align__(16) short lsA[128 * 64];
    __shared__ __align__(16) short lsB[128 * 64];

    int b = blockIdx.y;
    int v0 = blockIdx.x * 128;
    int tid = threadIdx.x;
    int lane = tid & 63;
    int w = tid >> 6;
    int mw = w & 1;
    int nw = w >> 1;
    int ln = lane & 15;
    int quad = lane >> 4;

    int srow = tid >> 1;
    int posBase = (tid & 1) * 4;

    floatx4 acc[4][4];
#pragma unroll
    for (int mi = 0; mi < 4; ++mi)
#pragma unroll
        for (int ni = 0; ni < 4; ++ni) acc[mi][ni] = (floatx4){0.f, 0.f, 0.f, 0.f};

    for (int kc = 0; kc < 4; ++kc) {
        __syncthreads();
        // stage A: wT rows (o)
#pragma unroll
        for (int j = 0; j < 4; ++j) {
            int pos = posBase + j;
            int g = pos ^ (srow & 7);
            uint4 val = *reinterpret_cast<const uint4*>(wT + (size_t)srow * 256 + kc * 64 + g * 8);
            *reinterpret_cast<uint4*>(&lsA[(srow * 8 + pos) * 8]) = val;
        }
        // stage B: xk bf16 direct copy
        {
            const ushort* xk = xbase + (size_t)kc * VN * FN;
            int v = v0 + srow;
            bool ok = (v < VN);
            const ushort* src = xk + (size_t)v * FN + b * CINN;
#pragma unroll
            for (int j = 0; j < 4; ++j) {
                int pos = posBase + j;
                int g = pos ^ (srow & 7);
                uint4 val;
                if (ok) val = *reinterpret_cast<const uint4*>(src + g * 8);
                else    val = make_uint4(0u, 0u, 0u, 0u);
                *reinterpret_cast<uint4*>(&lsB[(srow * 8 + pos) * 8]) = val;
            }
        }
        __syncthreads();

#pragma unroll
        for (int s = 0; s < 2; ++s) {
            short8 afr[4], bfr[4];
#pragma unroll
            for (int mi = 0; mi < 4; ++mi) {
                int r = mw * 64 + mi * 16 + ln;
                int pos = (s * 4 + quad) ^ (r & 7);
                afr[mi] = *reinterpret_cast<const short8*>(&lsA[(r * 8 + pos) * 8]);
            }
#pragma unroll
            for (int ni = 0; ni < 4; ++ni) {
                int r = nw * 64 + ni * 16 + ln;
                int pos = (s * 4 + quad) ^ (r & 7);
                bfr[ni] = *reinterpret_cast<const short8*>(&lsB[(r * 8 + pos) * 8]);
            }
#pragma unroll
            for (int mi = 0; mi < 4; ++mi)
#pragma unroll
                for (int ni = 0; ni < 4; ++ni)
                    acc[mi][ni] = __builtin_amdgcn_mfma_f32_16x16x32_bf16(
                        afr[mi], bfr[ni], acc[mi][ni], 0, 0, 0);
        }
    }

#pragma unroll
    for (int mi = 0; mi < 4; ++mi) {
#pragma unroll
        for (int r = 0; r < 4; ++r) {
            int o = mw * 64 + mi * 16 + quad * 4 + r;
            float bv = bias[o];
            size_t obase = (size_t)(b * COUTN + o) * VN;
#pragma unroll
            for (int ni = 0; ni < 4; ++ni) {
                int v = v0 + nw * 64 + ni * 16 + ln;
                if (v < VN) out[obase + v] = acc[mi][ni][r] + bv;
            }
        }
    }
}

// ---------------------------------------------------------------------------
extern "C" void kernel_launch(void* const* d_in, const int* in_sizes, int n_in,
                              void* d_out, int out_size, void* d_ws, size_t ws_size,
                              hipStream_t stream) {
    const float* x        = (const float*)d_in[0];
    const int*   lap_rows = (const int*)d_in[1];
    const int*   lap_cols = (const int*)d_in[2];
    const float* lap_vals = (const float*)d_in[3];
    const float* weight   = (const float*)d_in[4];
    const float* bias     = (const float*)d_in[5];
    float* out = (float*)d_out;

    char* ws = (char*)d_ws;
    ushort* x0 = (ushort*)ws;                        // 4 x (V,256) bf16, contiguous
    ushort* x1 = x0 + (size_t)VN * FN;
    ushort* x2 = x1 + (size_t)VN * FN;
    ushort* x3 = x2 + (size_t)VN * FN;
    size_t xbytes = (size_t)4 * VN * FN * sizeof(ushort);
    int* row_ptr = (int*)(ws + xbytes);              // V+1 ints
    size_t rp_end = xbytes + (size_t)(VN + 1) * sizeof(int);
    rp_end = (rp_end + 15) & ~(size_t)15;            // 16B align
    ushort* wT = (ushort*)(ws + rp_end);             // (128,256) bf16 = 64KB
    size_t wt_end = rp_end + (size_t)COUTN * FN * sizeof(ushort);
    unsigned long long* epack = (unsigned long long*)(ws + wt_end);  // 6.4MB

    setup_fused<<<RP_BLOCKS + WT_BLOCKS + EP_BLOCKS + TP_BLOCKS, 256, 0, stream>>>(
        lap_rows, row_ptr, weight, wT, x, x0, lap_cols, lap_vals, epack);
    // x1 = L x0
    spmm_cheb_bf16<<<(VN + 3) / 4, 256, 0, stream>>>(x1, x0, x0, row_ptr, epack, 1.f, 0.f);
    // x2 = 2 L x1 - x0
    spmm_cheb_bf16<<<(VN + 3) / 4, 256, 0, stream>>>(x2, x1, x0, row_ptr, epack, 2.f, -1.f);
    // x3 = 2 L x2 - x1
    spmm_cheb_bf16<<<(VN + 3) / 4, 256, 0, stream>>>(x3, x2, x1, row_ptr, epack, 2.f, -1.f);
    // out = sum_k xk @ Wk + bias  (MFMA)
    cheb_gemm_mfma<<<dim3((VN + 127) / 128, BN), 256, 0, stream>>>(out, x0, wT, bias);
}

// Round 9
// 378.707 us; speedup vs baseline: 1.3449x; 1.0156x over previous
//
#include <hip/hip_runtime.h>
#include <hip/hip_bf16.h>

#define VN 50000
#define EN 800000
#define BN 4
#define CINN 64
#define COUTN 128
#define KN 4
#define FN 256  // BN * CINN

typedef __attribute__((ext_vector_type(8))) short short8;
typedef __attribute__((ext_vector_type(8))) unsigned short ushort8;
typedef __attribute__((ext_vector_type(4))) float floatx4;

__device__ __forceinline__ float bf2f(unsigned short u) {
    union { unsigned int i; float f; } c;
    c.i = ((unsigned int)u) << 16;
    return c.f;
}
__device__ __forceinline__ unsigned short f2bf(float f) {
    __hip_bfloat16 h = __float2bfloat16(f);
    return *reinterpret_cast<unsigned short*>(&h);
}

typedef __attribute__((address_space(1))) const unsigned int guint;
typedef __attribute__((address_space(3))) unsigned int luint;
__device__ __forceinline__ void gload_lds16(const void* g, void* l) {
    // async global->LDS, 16B/lane; LDS dest = wave-uniform base + lane*16
    __builtin_amdgcn_global_load_lds((guint*)g, (luint*)l, 16, 0, 0);
}

#define RP_BLOCKS 196    // (VN+1+255)/256
#define WT_BLOCKS 128    // 128*256/256
#define EP_BLOCKS 3125   // EN/256
#define TP_BX 782        // (VN+63)/64
#define TP_BLOCKS (TP_BX * 4)

// ---------------------------------------------------------------------------
// Fused setup (round-4, known-good): row_ptr lower_bound; wT transpose+bf16;
// packed (col,val) 8B edge records; 64x64 x-transpose fp32->bf16 into
// interleaved layout x0[v][256].
// ---------------------------------------------------------------------------
__global__ __launch_bounds__(256) void setup_fused(const int* __restrict__ rows,
                                                   int* __restrict__ row_ptr,
                                                   const float* __restrict__ w,
                                                   ushort* __restrict__ wT,
                                                   const float* __restrict__ x,
                                                   ushort* __restrict__ x0,
                                                   const int* __restrict__ cols,
                                                   const float* __restrict__ vals,
                                                   unsigned long long* __restrict__ epack) {
    __shared__ float tile[64][65];
    int blk = blockIdx.x;
    int tid = threadIdx.x;
    if (blk < RP_BLOCKS) {
        int v = blk * 256 + tid;
        if (v > VN) return;
        int lo = 0, hi = EN;
        while (lo < hi) {
            int mid = (lo + hi) >> 1;
            if (rows[mid] < v) lo = mid + 1; else hi = mid;
        }
        row_ptr[v] = lo;
        return;
    }
    if (blk < RP_BLOCKS + WT_BLOCKS) {
        int idx = (blk - RP_BLOCKS) * 256 + tid;  // 32768 total
        int o = idx >> 8;
        int kk = idx & 255;
        wT[idx] = f2bf(w[(size_t)kk * COUTN + o]);
        return;
    }
    if (blk < RP_BLOCKS + WT_BLOCKS + EP_BLOCKS) {
        int idx = (blk - RP_BLOCKS - WT_BLOCKS) * 256 + tid;  // 800000 total
        unsigned int c = (unsigned int)cols[idx];
        unsigned int wv = __float_as_uint(vals[idx]);
        epack[idx] = ((unsigned long long)wv << 32) | (unsigned long long)c;
        return;
    }
    int t = blk - RP_BLOCKS - WT_BLOCKS - EP_BLOCKS;
    int v0 = (t % TP_BX) * 64;
    int f0 = (t / TP_BX) * 64;
    int tx = tid & 63;
    int ty = tid >> 6;
#pragma unroll
    for (int r = 0; r < 16; ++r) {
        int f = f0 + ty + r * 4;
        int v = v0 + tx;
        if (v < VN) tile[ty + r * 4][tx] = x[(size_t)f * VN + v];
    }
    __syncthreads();
#pragma unroll
    for (int r = 0; r < 16; ++r) {
        int v = v0 + ty + r * 4;
        int f = f0 + tx;
        if (v < VN) x0[(size_t)v * FN + f] = f2bf(tile[tx][ty + r * 4]);
    }
}

// ---------------------------------------------------------------------------
// bf16 SpMM (EXACT round-4, known-good 60.7us). r8 falsified latency-bound
// (8-deep pipeline: occupancy 68->42%, dur flat) and FETCH=190MB = 8 XCD x
// 25.6MB = compulsory L2-replication floor -> spmm is at the L3->L2 path
// roofline for this algorithm shape. Do not re-touch without an XCD-pinning
// mechanism (falsified 3x) or a col-bucketed streaming redesign.
// ---------------------------------------------------------------------------
__global__ __launch_bounds__(256) void spmm_cheb_bf16(ushort* __restrict__ out,
                                                      const ushort* __restrict__ z,
                                                      const ushort* __restrict__ prev,
                                                      const int* __restrict__ row_ptr,
                                                      const unsigned long long* __restrict__ epack,
                                                      float alpha, float beta) {
    int row = (int)((blockIdx.x * blockDim.x + threadIdx.x) >> 6);
    int lane = threadIdx.x & 63;
    if (row >= VN) return;
    int e0 = row_ptr[row];
    int e1 = row_ptr[row + 1];
    int half = lane >> 5;        // 0: even edges, 1: odd edges
    int fl = (lane & 31) * 8;    // 8 features per lane

    float acc0[8], acc1[8];
#pragma unroll
    for (int j = 0; j < 8; ++j) { acc0[j] = 0.f; acc1[j] = 0.f; }

    int e = e0 + half;
    // 4-deep main loop: 4 gathers in flight per half
    for (; e + 6 < e1; e += 8) {
        unsigned long long d0 = epack[e];
        unsigned long long d1 = epack[e + 2];
        unsigned long long d2 = epack[e + 4];
        unsigned long long d3 = epack[e + 6];
        ushort8 z0 = *reinterpret_cast<const ushort8*>(z + (size_t)(unsigned int)d0 * FN + fl);
        ushort8 z1 = *reinterpret_cast<const ushort8*>(z + (size_t)(unsigned int)d1 * FN + fl);
        ushort8 z2 = *reinterpret_cast<const ushort8*>(z + (size_t)(unsigned int)d2 * FN + fl);
        ushort8 z3 = *reinterpret_cast<const ushort8*>(z + (size_t)(unsigned int)d3 * FN + fl);
        float w0 = __uint_as_float((unsigned int)(d0 >> 32));
        float w1 = __uint_as_float((unsigned int)(d1 >> 32));
        float w2 = __uint_as_float((unsigned int)(d2 >> 32));
        float w3 = __uint_as_float((unsigned int)(d3 >> 32));
#pragma unroll
        for (int j = 0; j < 8; ++j) acc0[j] += w0 * bf2f(z0[j]);
#pragma unroll
        for (int j = 0; j < 8; ++j) acc1[j] += w1 * bf2f(z1[j]);
#pragma unroll
        for (int j = 0; j < 8; ++j) acc0[j] += w2 * bf2f(z2[j]);
#pragma unroll
        for (int j = 0; j < 8; ++j) acc1[j] += w3 * bf2f(z3[j]);
    }
    // 2-deep remainder
    for (; e + 2 < e1; e += 4) {
        unsigned long long d0 = epack[e];
        unsigned long long d1 = epack[e + 2];
        ushort8 z0 = *reinterpret_cast<const ushort8*>(z + (size_t)(unsigned int)d0 * FN + fl);
        ushort8 z1 = *reinterpret_cast<const ushort8*>(z + (size_t)(unsigned int)d1 * FN + fl);
        float w0 = __uint_as_float((unsigned int)(d0 >> 32));
        float w1 = __uint_as_float((unsigned int)(d1 >> 32));
#pragma unroll
        for (int j = 0; j < 8; ++j) acc0[j] += w0 * bf2f(z0[j]);
#pragma unroll
        for (int j = 0; j < 8; ++j) acc1[j] += w1 * bf2f(z1[j]);
    }
    for (; e < e1; e += 2) {
        unsigned long long d0 = epack[e];
        ushort8 z0 = *reinterpret_cast<const ushort8*>(z + (size_t)(unsigned int)d0 * FN + fl);
        float w0 = __uint_as_float((unsigned int)(d0 >> 32));
#pragma unroll
        for (int j = 0; j < 8; ++j) acc0[j] += w0 * bf2f(z0[j]);
    }
#pragma unroll
    for (int j = 0; j < 8; ++j) acc0[j] += acc1[j];
    // butterfly: merge even/odd halves
#pragma unroll
    for (int j = 0; j < 8; ++j) acc0[j] += __shfl(acc0[j], lane ^ 32);

    if (half == 0) {
        ushort8 res;
        if (beta != 0.f) {
            ushort8 pv = *reinterpret_cast<const ushort8*>(prev + (size_t)row * FN + fl);
#pragma unroll
            for (int j = 0; j < 8; ++j)
                res[j] = f2bf(alpha * acc0[j] + beta * bf2f(pv[j]));
        } else {
#pragma unroll
            for (int j = 0; j < 8; ++j)
                res[j] = f2bf(alpha * acc0[j]);
        }
        *reinterpret_cast<ushort8*>(out + (size_t)row * FN + fl) = res;
    }
}

// ---------------------------------------------------------------------------
// MFMA GEMM v3: v1 structure + global_load_lds DOUBLE BUFFER (T3-lite).
// Register prefetch failed twice (r5/r7: spill-like WRITE blowup); this is
// the no-VGPR-round-trip path. The LDS image is byte-identical to v1's
// XOR-swizzled layout: chunk c (1KB) covers rows r=c*8+(l>>3); lane l lands
// at pos p=l&7, so its GLOBAL source is pre-swizzled to granule
// g = (l&7)^(l>>3) = p^(r&7) (rule #21: linear dest + inverse-swz source +
// swz on read). ds_read/MFMA/epilogue unchanged from the verified v1.
// One __syncthreads per kc (drains vmcnt -> staged buffer ready) instead of
// two; stage of kc+1 is issued BEFORE kc's MFMA phase, hiding load latency.
// v>=VN staging lanes read garbage inside the workspace (x3 tail/row_ptr);
// they only affect C columns that are never stored.
// ---------------------------------------------------------------------------
__global__ __launch_bounds__(256) void cheb_gemm_mfma(float* __restrict__ out,
                                                      const ushort* __restrict__ xbase,
                                                      const ushort* __restrict__ wT,
                                                      const float* __restrict__ bias) {
    __shared__ __align__(16) short lds[2][16384];   // [buf][ A:8192 shorts | B:8192 shorts ]

    int b = blockIdx.y;
    int v0 = blockIdx.x * 128;
    int tid = threadIdx.x;
    int lane = tid & 63;
    int w = tid >> 6;
    int mw = w & 1;
    int nw = w >> 1;
    int ln = lane & 15;
    int quad = lane >> 4;

    // staging geometry: per wave, 4 chunks of 1KB each for A and for B
    int lr = lane >> 3;          // row within chunk (0..7)
    int lg = (lane & 7) ^ lr;    // pre-swizzled source granule

    floatx4 acc[4][4];
#pragma unroll
    for (int mi = 0; mi < 4; ++mi)
#pragma unroll
        for (int ni = 0; ni < 4; ++ni) acc[mi][ni] = (floatx4){0.f, 0.f, 0.f, 0.f};

#define STAGE(BUF, KC)                                                              \
    {                                                                               \
        const ushort* xk = xbase + (size_t)(KC) * VN * FN;                          \
        _Pragma("unroll")                                                           \
        for (int j = 0; j < 4; ++j) {                                               \
            int c = w * 4 + j;                                                      \
            int r = c * 8 + lr;                                                     \
            gload_lds16(wT + (size_t)r * 256 + (KC) * 64 + lg * 8,                  \
                        &lds[BUF][c * 512]);                                        \
            gload_lds16(xk + (size_t)(v0 + r) * FN + b * CINN + lg * 8,             \
                        &lds[BUF][8192 + c * 512]);                                 \
        }                                                                           \
    }

    int cur = 0;
    STAGE(0, 0);
    __syncthreads();   // drain vmcnt: buf0 ready

    for (int kc = 0; kc < 4; ++kc) {
        if (kc < 3) STAGE(cur ^ 1, kc + 1);   // issue next-tile loads first

#pragma unroll
        for (int s = 0; s < 2; ++s) {
            short8 afr[4], bfr[4];
#pragma unroll
            for (int mi = 0; mi < 4; ++mi) {
                int r = mw * 64 + mi * 16 + ln;
                int pos = (s * 4 + quad) ^ (r & 7);
                afr[mi] = *reinterpret_cast<const short8*>(&lds[cur][(r * 8 + pos) * 8]);
            }
#pragma unroll
            for (int ni = 0; ni < 4; ++ni) {
                int r = nw * 64 + ni * 16 + ln;
                int pos = (s * 4 + quad) ^ (r & 7);
                bfr[ni] = *reinterpret_cast<const short8*>(&lds[cur][8192 + (r * 8 + pos) * 8]);
            }
#pragma unroll
            for (int mi = 0; mi < 4; ++mi)
#pragma unroll
                for (int ni = 0; ni < 4; ++ni)
                    acc[mi][ni] = __builtin_amdgcn_mfma_f32_16x16x32_bf16(
                        afr[mi], bfr[ni], acc[mi][ni], 0, 0, 0);
        }
        __syncthreads();   // drains vmcnt(0)+lgkmcnt(0): next buffer staged, reads done
        cur ^= 1;
    }
#undef STAGE

    // epilogue (v1, unchanged): 16 consecutive-v lanes x 4B = full 64B lines
#pragma unroll
    for (int mi = 0; mi < 4; ++mi) {
#pragma unroll
        for (int r = 0; r < 4; ++r) {
            int o = mw * 64 + mi * 16 + quad * 4 + r;
            float bv = bias[o];
            size_t obase = (size_t)(b * COUTN + o) * VN;
#pragma unroll
            for (int ni = 0; ni < 4; ++ni) {
                int v = v0 + nw * 64 + ni * 16 + ln;
                if (v < VN) out[obase + v] = acc[mi][ni][r] + bv;
            }
        }
    }
}

// ---------------------------------------------------------------------------
extern "C" void kernel_launch(void* const* d_in, const int* in_sizes, int n_in,
                              void* d_out, int out_size, void* d_ws, size_t ws_size,
                              hipStream_t stream) {
    const float* x        = (const float*)d_in[0];
    const int*   lap_rows = (const int*)d_in[1];
    const int*   lap_cols = (const int*)d_in[2];
    const float* lap_vals = (const float*)d_in[3];
    const float* weight   = (const float*)d_in[4];
    const float* bias     = (const float*)d_in[5];
    float* out = (float*)d_out;

    char* ws = (char*)d_ws;
    ushort* x0 = (ushort*)ws;                        // 4 x (V,256) bf16, contiguous
    ushort* x1 = x0 + (size_t)VN * FN;
    ushort* x2 = x1 + (size_t)VN * FN;
    ushort* x3 = x2 + (size_t)VN * FN;
    size_t xbytes = (size_t)4 * VN * FN * sizeof(ushort);
    int* row_ptr = (int*)(ws + xbytes);              // V+1 ints
    size_t rp_end = xbytes + (size_t)(VN + 1) * sizeof(int);
    rp_end = (rp_end + 15) & ~(size_t)15;            // 16B align
    ushort* wT = (ushort*)(ws + rp_end);             // (128,256) bf16 = 64KB
    size_t wt_end = rp_end + (size_t)COUTN * FN * sizeof(ushort);
    unsigned long long* epack = (unsigned long long*)(ws + wt_end);  // 6.4MB

    setup_fused<<<RP_BLOCKS + WT_BLOCKS + EP_BLOCKS + TP_BLOCKS, 256, 0, stream>>>(
        lap_rows, row_ptr, weight, wT, x, x0, lap_cols, lap_vals, epack);
    // x1 = L x0
    spmm_cheb_bf16<<<(VN + 3) / 4, 256, 0, stream>>>(x1, x0, x0, row_ptr, epack, 1.f, 0.f);
    // x2 = 2 L x1 - x0
    spmm_cheb_bf16<<<(VN + 3) / 4, 256, 0, stream>>>(x2, x1, x0, row_ptr, epack, 2.f, -1.f);
    // x3 = 2 L x2 - x1
    spmm_cheb_bf16<<<(VN + 3) / 4, 256, 0, stream>>>(x3, x2, x1, row_ptr, epack, 2.f, -1.f);
    // out = sum_k xk @ Wk + bias  (MFMA)
    cheb_gemm_mfma<<<dim3((VN + 127) / 128, BN), 256, 0, stream>>>(out, x0, wT, bias);
}